// Round 3
// baseline (1878.378 us; speedup 1.0000x reference)
//
#include <hip/hip_runtime.h>

#define NB 16
#define NL 1024
#define ND 64
#define NW 20
#define THR 0.3f

typedef float f32x4 __attribute__((ext_vector_type(4)));

// One block = one wave (64 threads) per (b,l). Each thread computes an 8x8
// tile of the 64x64 correlation/adjacency matrix.
__global__ __launch_bounds__(64, 4) void dyn_corr_kernel(
    const float* __restrict__ x, float* __restrict__ out)
{
    const int bl = blockIdx.x;          // 0..16383
    const int b  = bl >> 10;
    const int l  = bl & (NL - 1);
    const int t  = threadIdx.x;         // 0..63

    __shared__ float win[NW][ND];       // 5120 B, centered in place
    __shared__ float meanv[ND];
    __shared__ float diag[ND];

    const float* xb = x + ((size_t)b * NL) * ND;

    // --- stage window as float4 slots (320 slots), coalesced ---
    #pragma unroll
    for (int i = 0; i < 5; ++i) {
        int s    = t + i * 64;          // 0..319
        int w    = s >> 4;
        int c4   = (s & 15) << 2;       // float col
        int lsrc = l - (NW - 1) + w;
        f32x4 v = {0.f, 0.f, 0.f, 0.f};
        if (lsrc >= 0) v = *(const f32x4*)&xb[(size_t)lsrc * ND + c4];
        *(f32x4*)&win[w][c4] = v;
    }
    __syncthreads();

    // --- per-feature mean over 20 rows (padded zeros included, as jnp.pad) ---
    {
        float s = 0.0f;
        #pragma unroll
        for (int w = 0; w < NW; ++w) s += win[w][t];
        meanv[t] = s * (1.0f / NW);
    }
    __syncthreads();

    // --- center in place (padded rows become -mean, as in reference) ---
    #pragma unroll
    for (int i = 0; i < 5; ++i) {
        int s  = t + i * 64;
        int w  = s >> 4;
        int c4 = (s & 15) << 2;
        f32x4 v = *(f32x4*)&win[w][c4];
        f32x4 m = *(f32x4*)&meanv[c4];
        v -= m;
        *(f32x4*)&win[w][c4] = v;
    }
    __syncthreads();

    // --- 8x8 cov tile per thread ---
    const int tr = t >> 3;              // 0..7
    const int tc = t & 7;               // 0..7
    const int d0 = tr << 3;
    const int e0 = tc << 3;

    float acc[8][8] = {};
    #pragma unroll
    for (int w = 0; w < NW; ++w) {
        f32x4 a0 = *(const f32x4*)&win[w][d0];
        f32x4 a1 = *(const f32x4*)&win[w][d0 + 4];
        f32x4 b0 = *(const f32x4*)&win[w][e0];
        f32x4 b1 = *(const f32x4*)&win[w][e0 + 4];
        float cd[8] = {a0.x, a0.y, a0.z, a0.w, a1.x, a1.y, a1.z, a1.w};
        float ce[8] = {b0.x, b0.y, b0.z, b0.w, b1.x, b1.y, b1.z, b1.w};
        #pragma unroll
        for (int i = 0; i < 8; ++i)
            #pragma unroll
            for (int j = 0; j < 8; ++j)
                acc[i][j] = fmaf(cd[i], ce[j], acc[i][j]);
    }

    const float inv = 1.0f / (NW - 1);

    // diagonal tiles publish cov[d][d]
    if (tr == tc) {
        #pragma unroll
        for (int i = 0; i < 8; ++i) diag[d0 + i] = acc[i][i] * inv;
    }
    __syncthreads();

    float sd[8], se[8];
    #pragma unroll
    for (int i = 0; i < 8; ++i) {
        sd[i] = sqrtf(diag[d0 + i]);
        se[i] = sqrtf(diag[e0 + i]);
    }

    // --- normalize + relu(|corr| - 0.3), nontemporal f32x4 stores ---
    float* ob = out + (size_t)bl * (ND * ND);
    #pragma unroll
    for (int i = 0; i < 8; ++i) {
        f32x4 o0, o1;
        float v;
        v = fabsf(__fdividef(acc[i][0] * inv, sd[i] * se[0] + 1e-8f)) - THR; o0.x = fmaxf(v, 0.0f);
        v = fabsf(__fdividef(acc[i][1] * inv, sd[i] * se[1] + 1e-8f)) - THR; o0.y = fmaxf(v, 0.0f);
        v = fabsf(__fdividef(acc[i][2] * inv, sd[i] * se[2] + 1e-8f)) - THR; o0.z = fmaxf(v, 0.0f);
        v = fabsf(__fdividef(acc[i][3] * inv, sd[i] * se[3] + 1e-8f)) - THR; o0.w = fmaxf(v, 0.0f);
        v = fabsf(__fdividef(acc[i][4] * inv, sd[i] * se[4] + 1e-8f)) - THR; o1.x = fmaxf(v, 0.0f);
        v = fabsf(__fdividef(acc[i][5] * inv, sd[i] * se[5] + 1e-8f)) - THR; o1.y = fmaxf(v, 0.0f);
        v = fabsf(__fdividef(acc[i][6] * inv, sd[i] * se[6] + 1e-8f)) - THR; o1.z = fmaxf(v, 0.0f);
        v = fabsf(__fdividef(acc[i][7] * inv, sd[i] * se[7] + 1e-8f)) - THR; o1.w = fmaxf(v, 0.0f);
        __builtin_nontemporal_store(o0, (f32x4*)&ob[(d0 + i) * ND + e0]);
        __builtin_nontemporal_store(o1, (f32x4*)&ob[(d0 + i) * ND + e0 + 4]);
    }
}

extern "C" void kernel_launch(void* const* d_in, const int* in_sizes, int n_in,
                              void* d_out, int out_size, void* d_ws, size_t ws_size,
                              hipStream_t stream) {
    const float* x = (const float*)d_in[0];
    float* out = (float*)d_out;
    dim3 grid(NB * NL);
    dim3 block(64);
    hipLaunchKernelGGL(dyn_corr_kernel, grid, block, 0, stream, x, out);
}

// Round 4
// 1146.775 us; speedup vs baseline: 1.6380x; 1.6380x over previous
//
#include <hip/hip_runtime.h>

#define NB 16
#define NL 1024
#define ND 64
#define NW 20
#define THR 0.3f

typedef float f32x4 __attribute__((ext_vector_type(4)));

// One block = one wave (64 threads) per (b,l). Each thread computes an 8x8
// tile of the 64x64 correlation/adjacency matrix.
// launch_bounds(64,3): VGPR cap ~170 — acc[8][8] (64 regs) + fragments must
// stay in registers. (64,4) capped at 128->compiler spilled acc to scratch:
// R3 showed 7 GB/dispatch of scratch traffic, 17x slowdown.
__global__ __launch_bounds__(64, 3) void dyn_corr_kernel(
    const float* __restrict__ x, float* __restrict__ out)
{
    const int bl = blockIdx.x;          // 0..16383
    const int b  = bl >> 10;
    const int l  = bl & (NL - 1);
    const int t  = threadIdx.x;         // 0..63

    __shared__ float win[NW][ND];       // 5120 B, centered in place
    __shared__ float meanv[ND];
    __shared__ float diag[ND];

    const float* xb = x + ((size_t)b * NL) * ND;

    // --- stage window as float4 slots (320 slots), coalesced ---
    #pragma unroll
    for (int i = 0; i < 5; ++i) {
        int s    = t + i * 64;          // 0..319
        int w    = s >> 4;
        int c4   = (s & 15) << 2;       // float col
        int lsrc = l - (NW - 1) + w;
        f32x4 v = {0.f, 0.f, 0.f, 0.f};
        if (lsrc >= 0) v = *(const f32x4*)&xb[(size_t)lsrc * ND + c4];
        *(f32x4*)&win[w][c4] = v;
    }
    __syncthreads();

    // --- per-feature mean over 20 rows (padded zeros included, as jnp.pad) ---
    {
        float s = 0.0f;
        #pragma unroll
        for (int w = 0; w < NW; ++w) s += win[w][t];
        meanv[t] = s * (1.0f / NW);
    }
    __syncthreads();

    // --- center in place (padded rows become -mean, as in reference) ---
    #pragma unroll
    for (int i = 0; i < 5; ++i) {
        int s  = t + i * 64;
        int w  = s >> 4;
        int c4 = (s & 15) << 2;
        f32x4 v = *(f32x4*)&win[w][c4];
        f32x4 m = *(f32x4*)&meanv[c4];
        v -= m;
        *(f32x4*)&win[w][c4] = v;
    }
    __syncthreads();

    // --- 8x8 cov tile per thread ---
    const int tr = t >> 3;              // 0..7
    const int tc = t & 7;               // 0..7
    const int d0 = tr << 3;
    const int e0 = tc << 3;

    float acc[8][8] = {};
    #pragma unroll
    for (int w = 0; w < NW; ++w) {
        f32x4 a0 = *(const f32x4*)&win[w][d0];
        f32x4 a1 = *(const f32x4*)&win[w][d0 + 4];
        f32x4 b0 = *(const f32x4*)&win[w][e0];
        f32x4 b1 = *(const f32x4*)&win[w][e0 + 4];
        float cd[8] = {a0.x, a0.y, a0.z, a0.w, a1.x, a1.y, a1.z, a1.w};
        float ce[8] = {b0.x, b0.y, b0.z, b0.w, b1.x, b1.y, b1.z, b1.w};
        #pragma unroll
        for (int i = 0; i < 8; ++i)
            #pragma unroll
            for (int j = 0; j < 8; ++j)
                acc[i][j] = fmaf(cd[i], ce[j], acc[i][j]);
    }

    const float inv = 1.0f / (NW - 1);

    // diagonal tiles publish cov[d][d]
    if (tr == tc) {
        #pragma unroll
        for (int i = 0; i < 8; ++i) diag[d0 + i] = acc[i][i] * inv;
    }
    __syncthreads();

    float sd[8], se[8];
    #pragma unroll
    for (int i = 0; i < 8; ++i) {
        sd[i] = sqrtf(diag[d0 + i]);
        se[i] = sqrtf(diag[e0 + i]);
    }

    // --- normalize + relu(|corr| - 0.3), nontemporal f32x4 stores ---
    float* ob = out + (size_t)bl * (ND * ND);
    #pragma unroll
    for (int i = 0; i < 8; ++i) {
        f32x4 o0, o1;
        float v;
        v = fabsf(__fdividef(acc[i][0] * inv, sd[i] * se[0] + 1e-8f)) - THR; o0.x = fmaxf(v, 0.0f);
        v = fabsf(__fdividef(acc[i][1] * inv, sd[i] * se[1] + 1e-8f)) - THR; o0.y = fmaxf(v, 0.0f);
        v = fabsf(__fdividef(acc[i][2] * inv, sd[i] * se[2] + 1e-8f)) - THR; o0.z = fmaxf(v, 0.0f);
        v = fabsf(__fdividef(acc[i][3] * inv, sd[i] * se[3] + 1e-8f)) - THR; o0.w = fmaxf(v, 0.0f);
        v = fabsf(__fdividef(acc[i][4] * inv, sd[i] * se[4] + 1e-8f)) - THR; o1.x = fmaxf(v, 0.0f);
        v = fabsf(__fdividef(acc[i][5] * inv, sd[i] * se[5] + 1e-8f)) - THR; o1.y = fmaxf(v, 0.0f);
        v = fabsf(__fdividef(acc[i][6] * inv, sd[i] * se[6] + 1e-8f)) - THR; o1.z = fmaxf(v, 0.0f);
        v = fabsf(__fdividef(acc[i][7] * inv, sd[i] * se[7] + 1e-8f)) - THR; o1.w = fmaxf(v, 0.0f);
        __builtin_nontemporal_store(o0, (f32x4*)&ob[(d0 + i) * ND + e0]);
        __builtin_nontemporal_store(o1, (f32x4*)&ob[(d0 + i) * ND + e0 + 4]);
    }
}

extern "C" void kernel_launch(void* const* d_in, const int* in_sizes, int n_in,
                              void* d_out, int out_size, void* d_ws, size_t ws_size,
                              hipStream_t stream) {
    const float* x = (const float*)d_in[0];
    float* out = (float*)d_out;
    dim3 grid(NB * NL);
    dim3 block(64);
    hipLaunchKernelGGL(dyn_corr_kernel, grid, block, 0, stream, x, out);
}

// Round 5
// 631.773 us; speedup vs baseline: 2.9732x; 1.8152x over previous
//
#include <hip/hip_runtime.h>

#define NB 16
#define NL 1024
#define ND 64
#define NW 20
#define THR 0.3f

typedef float f32x4 __attribute__((ext_vector_type(4)));

// One block = 128 threads (2 waves) per (b,l). Each thread computes a 4x8
// tile of the 64x64 correlation/adjacency matrix: acc = 32 floats/thread.
// NOTE: no __launch_bounds__ — R3/R4 showed that waves-per-EU hints make the
// allocator target high occupancy and spill the accumulator to scratch
// (VGPR_Count 64/84, ~4-7 GB/dispatch scratch traffic, 10-17x slowdown).
__global__ void dyn_corr_kernel(
    const float* __restrict__ x, float* __restrict__ out)
{
    const int bl = blockIdx.x;          // 0..16383
    const int b  = bl >> 10;
    const int l  = bl & (NL - 1);
    const int t  = threadIdx.x;         // 0..127

    __shared__ float win[NW][ND];       // 5120 B, centered in place
    __shared__ float meanv[ND];
    __shared__ float diag[ND];

    const float* xb = x + ((size_t)b * NL) * ND;

    // --- stage window as float4 slots (320 slots), coalesced ---
    #pragma unroll
    for (int i = 0; i < 3; ++i) {
        int s = t + i * 128;            // 0..383, valid < 320
        if (s < 320) {
            int w    = s >> 4;
            int c4   = (s & 15) << 2;
            int lsrc = l - (NW - 1) + w;
            f32x4 v = {0.f, 0.f, 0.f, 0.f};
            if (lsrc >= 0) v = *(const f32x4*)&xb[(size_t)lsrc * ND + c4];
            *(f32x4*)&win[w][c4] = v;
        }
    }
    __syncthreads();

    // --- per-feature mean over 20 rows (padded zeros included, as jnp.pad) ---
    if (t < ND) {
        float s = 0.0f;
        #pragma unroll
        for (int w = 0; w < NW; ++w) s += win[w][t];
        meanv[t] = s * (1.0f / NW);
    }
    __syncthreads();

    // --- center in place (padded rows become -mean, as in reference) ---
    #pragma unroll
    for (int i = 0; i < 3; ++i) {
        int s = t + i * 128;
        if (s < 320) {
            int w  = s >> 4;
            int c4 = (s & 15) << 2;
            f32x4 v = *(f32x4*)&win[w][c4];
            f32x4 m = *(f32x4*)&meanv[c4];
            v -= m;
            *(f32x4*)&win[w][c4] = v;
        }
    }
    __syncthreads();

    // --- 4x8 cov tile per thread ---
    const int tr = t >> 3;              // 0..15 -> rows 4*tr..+3
    const int tc = t & 7;               // 0..7  -> cols 8*tc..+7
    const int d0 = tr << 2;
    const int e0 = tc << 3;

    float acc[4][8] = {};
    #pragma unroll
    for (int w = 0; w < NW; ++w) {
        f32x4 a0 = *(const f32x4*)&win[w][d0];
        f32x4 b0 = *(const f32x4*)&win[w][e0];
        f32x4 b1 = *(const f32x4*)&win[w][e0 + 4];
        float cd[4] = {a0.x, a0.y, a0.z, a0.w};
        float ce[8] = {b0.x, b0.y, b0.z, b0.w, b1.x, b1.y, b1.z, b1.w};
        #pragma unroll
        for (int i = 0; i < 4; ++i)
            #pragma unroll
            for (int j = 0; j < 8; ++j)
                acc[i][j] = fmaf(cd[i], ce[j], acc[i][j]);
    }

    const float inv = 1.0f / (NW - 1);

    // tiles straddling the diagonal publish cov[d][d] (col 8tc <= row < 8tc+8)
    if (tc == (tr >> 1)) {
        #pragma unroll
        for (int i = 0; i < 4; ++i) {
            int d = d0 + i;
            diag[d] = acc[i][d - e0] * inv;
        }
    }
    __syncthreads();

    float sd[4], se[8];
    #pragma unroll
    for (int i = 0; i < 4; ++i) sd[i] = sqrtf(diag[d0 + i]);
    #pragma unroll
    for (int j = 0; j < 8; ++j) se[j] = sqrtf(diag[e0 + j]);

    // --- normalize + relu(|corr| - 0.3), f32x4 stores ---
    float* ob = out + (size_t)bl * (ND * ND);
    #pragma unroll
    for (int i = 0; i < 4; ++i) {
        f32x4 o0, o1;
        float v;
        v = fabsf(__fdividef(acc[i][0] * inv, sd[i] * se[0] + 1e-8f)) - THR; o0.x = fmaxf(v, 0.0f);
        v = fabsf(__fdividef(acc[i][1] * inv, sd[i] * se[1] + 1e-8f)) - THR; o0.y = fmaxf(v, 0.0f);
        v = fabsf(__fdividef(acc[i][2] * inv, sd[i] * se[2] + 1e-8f)) - THR; o0.z = fmaxf(v, 0.0f);
        v = fabsf(__fdividef(acc[i][3] * inv, sd[i] * se[3] + 1e-8f)) - THR; o0.w = fmaxf(v, 0.0f);
        v = fabsf(__fdividef(acc[i][4] * inv, sd[i] * se[4] + 1e-8f)) - THR; o1.x = fmaxf(v, 0.0f);
        v = fabsf(__fdividef(acc[i][5] * inv, sd[i] * se[5] + 1e-8f)) - THR; o1.y = fmaxf(v, 0.0f);
        v = fabsf(__fdividef(acc[i][6] * inv, sd[i] * se[6] + 1e-8f)) - THR; o1.z = fmaxf(v, 0.0f);
        v = fabsf(__fdividef(acc[i][7] * inv, sd[i] * se[7] + 1e-8f)) - THR; o1.w = fmaxf(v, 0.0f);
        *(f32x4*)&ob[(d0 + i) * ND + e0]     = o0;
        *(f32x4*)&ob[(d0 + i) * ND + e0 + 4] = o1;
    }
}

extern "C" void kernel_launch(void* const* d_in, const int* in_sizes, int n_in,
                              void* d_out, int out_size, void* d_ws, size_t ws_size,
                              hipStream_t stream) {
    const float* x = (const float*)d_in[0];
    float* out = (float*)d_out;
    dim3 grid(NB * NL);
    dim3 block(128);
    hipLaunchKernelGGL(dyn_corr_kernel, grid, block, 0, stream, x, out);
}

// Round 6
// 72.876 us; speedup vs baseline: 25.7751x; 8.6692x over previous
//
#include <hip/hip_runtime.h>

#define NB 16
#define NL 1024
#define ND 64
#define NW 20
#define THR 0.3f

typedef float f32x4 __attribute__((ext_vector_type(4)));

// One block = 128 threads (2 waves) per (b,l). Each thread computes a 4x8
// tile of the 64x64 correlation/adjacency matrix: acc = 32 floats/thread.
// RULE: no runtime indexing into acc[][] anywhere (R5: acc[i][d-e0] demoted
// the whole accumulator to scratch -> VGPR_Count=32, 6x slowdown). Diagonal
// variances are recomputed directly from the centered window instead.
// NOTE: no __launch_bounds__ (R3/R4: occupancy hints made allocator spill).
__global__ void dyn_corr_kernel(
    const float* __restrict__ x, float* __restrict__ out)
{
    const int bl = blockIdx.x;          // 0..16383
    const int b  = bl >> 10;
    const int l  = bl & (NL - 1);
    const int t  = threadIdx.x;         // 0..127

    __shared__ float win[NW][ND];       // 5120 B, centered in place
    __shared__ float meanv[ND];
    __shared__ float rsd[ND];           // 1/(sqrt(cov[d][d]))-ish, see below

    const float* xb = x + ((size_t)b * NL) * ND;

    // --- stage window as float4 slots (320 slots), coalesced ---
    #pragma unroll
    for (int i = 0; i < 3; ++i) {
        int s = t + i * 128;            // 0..383, valid < 320
        if (s < 320) {
            int w    = s >> 4;
            int c4   = (s & 15) << 2;
            int lsrc = l - (NW - 1) + w;
            f32x4 v = {0.f, 0.f, 0.f, 0.f};
            if (lsrc >= 0) v = *(const f32x4*)&xb[(size_t)lsrc * ND + c4];
            *(f32x4*)&win[w][c4] = v;
        }
    }
    __syncthreads();

    // --- per-feature mean over 20 rows (padded zeros included, as jnp.pad) ---
    if (t < ND) {
        float s = 0.0f;
        #pragma unroll
        for (int w = 0; w < NW; ++w) s += win[w][t];
        meanv[t] = s * (1.0f / NW);
    }
    __syncthreads();

    // --- center in place (padded rows become -mean, as in reference) ---
    #pragma unroll
    for (int i = 0; i < 3; ++i) {
        int s = t + i * 128;
        if (s < 320) {
            int w  = s >> 4;
            int c4 = (s & 15) << 2;
            f32x4 v = *(f32x4*)&win[w][c4];
            f32x4 m = *(f32x4*)&meanv[c4];
            v -= m;
            *(f32x4*)&win[w][c4] = v;
        }
    }
    __syncthreads();

    // --- per-feature std (diagonal of cov) directly from centered window ---
    if (t < ND) {
        float s = 0.0f;
        #pragma unroll
        for (int w = 0; w < NW; ++w) {
            float c = win[w][t];
            s = fmaf(c, c, s);
        }
        rsd[t] = sqrtf(s * (1.0f / (NW - 1)));
    }
    __syncthreads();

    // --- 4x8 cov tile per thread (all indices compile-time after unroll) ---
    const int tr = t >> 3;              // 0..15 -> rows 4*tr..+3
    const int tc = t & 7;               // 0..7  -> cols 8*tc..+7
    const int d0 = tr << 2;
    const int e0 = tc << 3;

    float acc[4][8] = {};
    #pragma unroll
    for (int w = 0; w < NW; ++w) {
        f32x4 a0 = *(const f32x4*)&win[w][d0];
        f32x4 b0 = *(const f32x4*)&win[w][e0];
        f32x4 b1 = *(const f32x4*)&win[w][e0 + 4];
        float cd[4] = {a0.x, a0.y, a0.z, a0.w};
        float ce[8] = {b0.x, b0.y, b0.z, b0.w, b1.x, b1.y, b1.z, b1.w};
        #pragma unroll
        for (int i = 0; i < 4; ++i)
            #pragma unroll
            for (int j = 0; j < 8; ++j)
                acc[i][j] = fmaf(cd[i], ce[j], acc[i][j]);
    }

    const float inv = 1.0f / (NW - 1);

    float sd[4], se[8];
    #pragma unroll
    for (int i = 0; i < 4; ++i) sd[i] = rsd[d0 + i];
    #pragma unroll
    for (int j = 0; j < 8; ++j) se[j] = rsd[e0 + j];

    // --- normalize + relu(|corr| - 0.3), f32x4 stores ---
    float* ob = out + (size_t)bl * (ND * ND);
    #pragma unroll
    for (int i = 0; i < 4; ++i) {
        f32x4 o0, o1;
        float v;
        v = fabsf(__fdividef(acc[i][0] * inv, sd[i] * se[0] + 1e-8f)) - THR; o0.x = fmaxf(v, 0.0f);
        v = fabsf(__fdividef(acc[i][1] * inv, sd[i] * se[1] + 1e-8f)) - THR; o0.y = fmaxf(v, 0.0f);
        v = fabsf(__fdividef(acc[i][2] * inv, sd[i] * se[2] + 1e-8f)) - THR; o0.z = fmaxf(v, 0.0f);
        v = fabsf(__fdividef(acc[i][3] * inv, sd[i] * se[3] + 1e-8f)) - THR; o0.w = fmaxf(v, 0.0f);
        v = fabsf(__fdividef(acc[i][4] * inv, sd[i] * se[4] + 1e-8f)) - THR; o1.x = fmaxf(v, 0.0f);
        v = fabsf(__fdividef(acc[i][5] * inv, sd[i] * se[5] + 1e-8f)) - THR; o1.y = fmaxf(v, 0.0f);
        v = fabsf(__fdividef(acc[i][6] * inv, sd[i] * se[6] + 1e-8f)) - THR; o1.z = fmaxf(v, 0.0f);
        v = fabsf(__fdividef(acc[i][7] * inv, sd[i] * se[7] + 1e-8f)) - THR; o1.w = fmaxf(v, 0.0f);
        *(f32x4*)&ob[(d0 + i) * ND + e0]     = o0;
        *(f32x4*)&ob[(d0 + i) * ND + e0 + 4] = o1;
    }
}

extern "C" void kernel_launch(void* const* d_in, const int* in_sizes, int n_in,
                              void* d_out, int out_size, void* d_ws, size_t ws_size,
                              hipStream_t stream) {
    const float* x = (const float*)d_in[0];
    float* out = (float*)d_out;
    dim3 grid(NB * NL);
    dim3 block(128);
    hipLaunchKernelGGL(dyn_corr_kernel, grid, block, 0, stream, x, out);
}

// Round 7
// 62.322 us; speedup vs baseline: 30.1398x; 1.1693x over previous
//
#include <hip/hip_runtime.h>

#define NB 16
#define NL 1024
#define ND 64
#define NW 20
#define CH 8                    // l's per block (rolling)
#define THR 0.3f

typedef float f32x4 __attribute__((ext_vector_type(4)));

// Rolling-window version. One block = 128 threads per (b, 8-l chunk).
// cov(l) = (Sum x x^T - W m m^T)/(W-1): maintain raw Gram + row/col sums and
// sumsq in registers; step l->l+1 by adding the incoming row's outer product
// and subtracting the outgoing one (2 rows instead of 20).
// RULES (hard-won): no runtime indexing into any register array (R5: scratch
// demotion, 6x); no __launch_bounds__ occupancy hints (R3/R4: forced spill).
__global__ void dyn_corr_kernel(
    const float* __restrict__ x, float* __restrict__ out)
{
    const int blk = blockIdx.x;            // 0..2047
    const int b   = blk >> 7;              // 128 chunks per batch
    const int l0  = (blk & 127) * CH;
    const int t   = threadIdx.x;           // 0..127

    const int NROW = NW - 1 + CH;          // 27 staged rows: l0-19 .. l0+7
    __shared__ float win[NW - 1 + CH][ND]; // 27*64*4 = 6912 B, raw (uncentered)

    const float* xb = x + ((size_t)b * NL) * ND;

    // --- stage 27 rows (zeros for l<0), f32x4, coalesced ---
    #pragma unroll
    for (int i = 0; i < 4; ++i) {
        int s = t + i * 128;               // 0..511, valid < 432
        if (s < NROW * 16) {
            int w    = s >> 4;
            int c4   = (s & 15) << 2;
            int lsrc = l0 - (NW - 1) + w;
            f32x4 v = {0.f, 0.f, 0.f, 0.f};
            if (lsrc >= 0) v = *(const f32x4*)&xb[(size_t)lsrc * ND + c4];
            *(f32x4*)&win[w][c4] = v;
        }
    }
    __syncthreads();                       // win is read-only from here on

    const int tr = t >> 3;                 // 0..15 -> rows 4*tr..+3
    const int tc = t & 7;                  // 0..7  -> cols 8*tc..+7
    const int d0 = tr << 2;
    const int e0 = tc << 3;

    float acc[4][8] = {};                  // raw Gram tile
    float rs[4] = {}, rq[4] = {};          // row sum / sumsq
    float cs[8] = {}, cq[8] = {};          // col sum / sumsq

    // --- init: full first window, LDS rows 0..19 (= l0-19..l0) ---
    #pragma unroll
    for (int w = 0; w < NW; ++w) {
        f32x4 a0 = *(const f32x4*)&win[w][d0];
        f32x4 b0 = *(const f32x4*)&win[w][e0];
        f32x4 b1 = *(const f32x4*)&win[w][e0 + 4];
        float ar[4] = {a0.x, a0.y, a0.z, a0.w};
        float br[8] = {b0.x, b0.y, b0.z, b0.w, b1.x, b1.y, b1.z, b1.w};
        #pragma unroll
        for (int i = 0; i < 4; ++i) {
            rs[i] += ar[i];
            rq[i]  = fmaf(ar[i], ar[i], rq[i]);
            #pragma unroll
            for (int j = 0; j < 8; ++j)
                acc[i][j] = fmaf(ar[i], br[j], acc[i][j]);
        }
        #pragma unroll
        for (int j = 0; j < 8; ++j) {
            cs[j] += br[j];
            cq[j]  = fmaf(br[j], br[j], cq[j]);
        }
    }

    const float invW  = 1.0f / NW;
    const float inv19 = 1.0f / (NW - 1);
    float* obase = out + ((size_t)b * NL + l0) * (ND * ND);

    for (int s = 0; s < CH; ++s) {
        // --- epilogue for l = l0 + s ---
        float sdr[4], sdc[8], msc[8];
        #pragma unroll
        for (int i = 0; i < 4; ++i) {
            float var = (rq[i] - rs[i] * (rs[i] * invW)) * inv19;
            sdr[i] = sqrtf(var);
        }
        #pragma unroll
        for (int j = 0; j < 8; ++j) {
            msc[j] = cs[j] * invW;
            float var = (cq[j] - cs[j] * msc[j]) * inv19;
            sdc[j] = sqrtf(var);
        }
        float* ob = obase + (size_t)s * (ND * ND);
        #pragma unroll
        for (int i = 0; i < 4; ++i) {
            f32x4 o0, o1;
            float cv, v;
            cv = fmaf(-rs[i], msc[0], acc[i][0]) * inv19; v = fabsf(__fdividef(cv, sdr[i] * sdc[0] + 1e-8f)) - THR; o0.x = fmaxf(v, 0.0f);
            cv = fmaf(-rs[i], msc[1], acc[i][1]) * inv19; v = fabsf(__fdividef(cv, sdr[i] * sdc[1] + 1e-8f)) - THR; o0.y = fmaxf(v, 0.0f);
            cv = fmaf(-rs[i], msc[2], acc[i][2]) * inv19; v = fabsf(__fdividef(cv, sdr[i] * sdc[2] + 1e-8f)) - THR; o0.z = fmaxf(v, 0.0f);
            cv = fmaf(-rs[i], msc[3], acc[i][3]) * inv19; v = fabsf(__fdividef(cv, sdr[i] * sdc[3] + 1e-8f)) - THR; o0.w = fmaxf(v, 0.0f);
            cv = fmaf(-rs[i], msc[4], acc[i][4]) * inv19; v = fabsf(__fdividef(cv, sdr[i] * sdc[4] + 1e-8f)) - THR; o1.x = fmaxf(v, 0.0f);
            cv = fmaf(-rs[i], msc[5], acc[i][5]) * inv19; v = fabsf(__fdividef(cv, sdr[i] * sdc[5] + 1e-8f)) - THR; o1.y = fmaxf(v, 0.0f);
            cv = fmaf(-rs[i], msc[6], acc[i][6]) * inv19; v = fabsf(__fdividef(cv, sdr[i] * sdc[6] + 1e-8f)) - THR; o1.z = fmaxf(v, 0.0f);
            cv = fmaf(-rs[i], msc[7], acc[i][7]) * inv19; v = fabsf(__fdividef(cv, sdr[i] * sdc[7] + 1e-8f)) - THR; o1.w = fmaxf(v, 0.0f);
            *(f32x4*)&ob[(d0 + i) * ND + e0]     = o0;
            *(f32x4*)&ob[(d0 + i) * ND + e0 + 4] = o1;
        }

        // --- rolling update l -> l+1: add LDS row s+20, remove row s ---
        if (s < CH - 1) {
            f32x4 na0 = *(const f32x4*)&win[s + NW][d0];
            f32x4 nb0 = *(const f32x4*)&win[s + NW][e0];
            f32x4 nb1 = *(const f32x4*)&win[s + NW][e0 + 4];
            f32x4 oa0 = *(const f32x4*)&win[s][d0];
            f32x4 ob0 = *(const f32x4*)&win[s][e0];
            f32x4 ob1 = *(const f32x4*)&win[s][e0 + 4];
            float an[4] = {na0.x, na0.y, na0.z, na0.w};
            float bn[8] = {nb0.x, nb0.y, nb0.z, nb0.w, nb1.x, nb1.y, nb1.z, nb1.w};
            float ao[4] = {oa0.x, oa0.y, oa0.z, oa0.w};
            float bo[8] = {ob0.x, ob0.y, ob0.z, ob0.w, ob1.x, ob1.y, ob1.z, ob1.w};
            #pragma unroll
            for (int i = 0; i < 4; ++i) {
                rs[i] += an[i] - ao[i];
                rq[i]  = fmaf(an[i], an[i], fmaf(-ao[i], ao[i], rq[i]));
                #pragma unroll
                for (int j = 0; j < 8; ++j)
                    acc[i][j] = fmaf(an[i], bn[j], fmaf(-ao[i], bo[j], acc[i][j]));
            }
            #pragma unroll
            for (int j = 0; j < 8; ++j) {
                cs[j] += bn[j] - bo[j];
                cq[j]  = fmaf(bn[j], bn[j], fmaf(-bo[j], bo[j], cq[j]));
            }
        }
    }
}

extern "C" void kernel_launch(void* const* d_in, const int* in_sizes, int n_in,
                              void* d_out, int out_size, void* d_ws, size_t ws_size,
                              hipStream_t stream) {
    const float* x = (const float*)d_in[0];
    float* out = (float*)d_out;
    dim3 grid(NB * (NL / CH));
    dim3 block(128);
    hipLaunchKernelGGL(dyn_corr_kernel, grid, block, 0, stream, x, out);
}

// Round 9
// 62.031 us; speedup vs baseline: 30.2814x; 1.0047x over previous
//
#include <hip/hip_runtime.h>

#define NB 16
#define NL 1024
#define ND 64
#define NW 20
#define CH 16                   // l's per block (rolling)
#define THR 0.3f

typedef float f32x4 __attribute__((ext_vector_type(4)));

// Rolling-window, 256 threads per (b, 16-l chunk); each thread owns a 4x4
// tile. Raw Gram + row/col sum/sumsq in registers; step l->l+1 adds the
// incoming row's outer product and subtracts the outgoing one.
// EPILOGUE MUST keep the reference's denominator eps EXACTLY:
//   corr = cov / (sd_i*sd_j + 1e-8)
// (R8 factored it into rsqrt's -> absmax 0.7: at l=0 the window is rank-1
// (19 zero pads + 1 row), |corr|=1 for all pairs, and pairs with tiny
// std product rely on the +1e-8 to crush corr to ~0.)
// RULES: no runtime indexing into register arrays (R5: scratch demotion, 6x);
// no __launch_bounds__ occupancy hints (R3/R4: forced spill).
__global__ void dyn_corr_kernel(
    const float* __restrict__ x, float* __restrict__ out)
{
    const int blk = blockIdx.x;            // 0..1023
    const int b   = blk >> 6;              // 64 chunks per batch
    const int l0  = (blk & 63) * CH;
    const int t   = threadIdx.x;           // 0..255

    const int NROW = NW - 1 + CH;          // 35 staged rows: l0-19 .. l0+15
    __shared__ float win[NW - 1 + CH][ND]; // 8960 B, raw (uncentered)

    const float* xb = x + ((size_t)b * NL) * ND;

    // --- stage 35 rows (zeros for l<0), f32x4, coalesced ---
    #pragma unroll
    for (int i = 0; i < 3; ++i) {
        int s = t + i * 256;               // valid < 560
        if (s < NROW * 16) {
            int w    = s >> 4;
            int c4   = (s & 15) << 2;
            int lsrc = l0 - (NW - 1) + w;
            f32x4 v = {0.f, 0.f, 0.f, 0.f};
            if (lsrc >= 0) v = *(const f32x4*)&xb[(size_t)lsrc * ND + c4];
            *(f32x4*)&win[w][c4] = v;
        }
    }
    __syncthreads();                       // win read-only from here on

    const int tr = t >> 4;                 // 0..15 -> rows 4*tr..+3
    const int tc = t & 15;                 // 0..15 -> cols 4*tc..+3
    const int d0 = tr << 2;
    const int e0 = tc << 2;

    float acc[4][4] = {};                  // raw Gram tile
    float rs[4] = {}, rq[4] = {};          // row sum / sumsq
    float cs[4] = {}, cq[4] = {};          // col sum / sumsq

    // --- init: full first window, LDS rows 0..19 (= l0-19..l0) ---
    #pragma unroll
    for (int w = 0; w < NW; ++w) {
        f32x4 a0 = *(const f32x4*)&win[w][d0];
        f32x4 b0 = *(const f32x4*)&win[w][e0];
        float ar[4] = {a0.x, a0.y, a0.z, a0.w};
        float br[4] = {b0.x, b0.y, b0.z, b0.w};
        #pragma unroll
        for (int i = 0; i < 4; ++i) {
            rs[i] += ar[i];
            rq[i]  = fmaf(ar[i], ar[i], rq[i]);
            #pragma unroll
            for (int j = 0; j < 4; ++j)
                acc[i][j] = fmaf(ar[i], br[j], acc[i][j]);
        }
        #pragma unroll
        for (int j = 0; j < 4; ++j) {
            cs[j] += br[j];
            cq[j]  = fmaf(br[j], br[j], cq[j]);
        }
    }

    const float invW  = 1.0f / NW;
    const float inv19 = 1.0f / (NW - 1);
    float* obase = out + ((size_t)b * NL + l0) * (ND * ND);

    for (int s = 0; s < CH; ++s) {
        // --- epilogue for l = l0 + s (reference-exact eps semantics) ---
        float sd[4], se[4], mc[4];
        #pragma unroll
        for (int i = 0; i < 4; ++i) {
            float var = fmaf(-rs[i] * invW, rs[i], rq[i]) * inv19;
            sd[i] = sqrtf(var);
        }
        #pragma unroll
        for (int j = 0; j < 4; ++j) {
            mc[j] = cs[j] * invW;
            float var = fmaf(-cs[j], mc[j], cq[j]) * inv19;
            se[j] = sqrtf(var);
        }
        float* ob = obase + (size_t)s * (ND * ND);
        #pragma unroll
        for (int i = 0; i < 4; ++i) {
            f32x4 o;
            float cv;
            cv = fmaf(-rs[i], mc[0], acc[i][0]) * inv19;
            o.x = fmaxf(fabsf(__fdividef(cv, sd[i] * se[0] + 1e-8f)) - THR, 0.0f);
            cv = fmaf(-rs[i], mc[1], acc[i][1]) * inv19;
            o.y = fmaxf(fabsf(__fdividef(cv, sd[i] * se[1] + 1e-8f)) - THR, 0.0f);
            cv = fmaf(-rs[i], mc[2], acc[i][2]) * inv19;
            o.z = fmaxf(fabsf(__fdividef(cv, sd[i] * se[2] + 1e-8f)) - THR, 0.0f);
            cv = fmaf(-rs[i], mc[3], acc[i][3]) * inv19;
            o.w = fmaxf(fabsf(__fdividef(cv, sd[i] * se[3] + 1e-8f)) - THR, 0.0f);
            *(f32x4*)&ob[(d0 + i) * ND + e0] = o;
        }

        // --- rolling update l -> l+1: add LDS row s+20, remove row s ---
        if (s < CH - 1) {
            f32x4 na  = *(const f32x4*)&win[s + NW][d0];
            f32x4 nb  = *(const f32x4*)&win[s + NW][e0];
            f32x4 oa  = *(const f32x4*)&win[s][d0];
            f32x4 obv = *(const f32x4*)&win[s][e0];
            float an[4] = {na.x, na.y, na.z, na.w};
            float bn[4] = {nb.x, nb.y, nb.z, nb.w};
            float ao[4] = {oa.x, oa.y, oa.z, oa.w};
            float bo[4] = {obv.x, obv.y, obv.z, obv.w};
            #pragma unroll
            for (int i = 0; i < 4; ++i) {
                rs[i] += an[i] - ao[i];
                rq[i]  = fmaf(an[i], an[i], fmaf(-ao[i], ao[i], rq[i]));
                #pragma unroll
                for (int j = 0; j < 4; ++j)
                    acc[i][j] = fmaf(an[i], bn[j], fmaf(-ao[i], bo[j], acc[i][j]));
            }
            #pragma unroll
            for (int j = 0; j < 4; ++j) {
                cs[j] += bn[j] - bo[j];
                cq[j]  = fmaf(bn[j], bn[j], fmaf(-bo[j], bo[j], cq[j]));
            }
        }
    }
}

extern "C" void kernel_launch(void* const* d_in, const int* in_sizes, int n_in,
                              void* d_out, int out_size, void* d_ws, size_t ws_size,
                              hipStream_t stream) {
    const float* x = (const float*)d_in[0];
    float* out = (float*)d_out;
    dim3 grid(NB * (NL / CH));
    dim3 block(256);
    hipLaunchKernelGGL(dyn_corr_kernel, grid, block, 0, stream, x, out);
}